// Round 2
// baseline (1691.644 us; speedup 1.0000x reference)
//
#include <hip/hip_runtime.h>
#include <hip/hip_fp16.h>

// FFT cross-correlation via overlap-save, fp16 spectra, ws-size-adaptive chunking.
// signal (32,128,8192) f32, weight (128,128,2048) f32, bias (128) f32
// out[b,o,t] = sum_i sum_k s_pad[b,i,t+k]*w[o,i,k] + bias[o], t in [0,8192]
// Blocks of 4096 (hop 2048, 4 per batch row); real FFT via packed complex
// Stockham FFT of M=2048 (natural order). Spectra stored as __half2 (4B/bin).

#define THREADS 256
#define FP 2056   // padded bins per row (valid f=0..2048); row = 8224 B, 16B-aligned

struct alignas(16) H2x4 { __half2 h[4]; };

__device__ __forceinline__ float2 f2(float x, float y){ return make_float2(x, y); }
__device__ __forceinline__ __half2 pack2(float x, float y){ return __floats2half2_rn(x, y); }
__device__ __forceinline__ float2 unpack2(__half2 h){
  return make_float2(__low2float(h), __high2float(h));
}

// In-LDS Stockham radix-2 complex FFT, size 2048, 256 threads.
// sign=-1 fwd, +1 inv (unscaled). Twiddles via v_sin/v_cos (revolutions).
__device__ float2* fft2048(float2* A, float2* B, int tid, float sign){
  float2* src = A; float2* dst = B;
  #pragma unroll 1
  for (int s = 0; s < 11; ++s){
    const int Ls = 1 << s;
    const float crev = sign * 0.5f / (float)Ls;  // rev per p: angle = sign*pi*p/Ls
    __syncthreads();
    #pragma unroll
    for (int r = 0; r < 4; ++r){
      int j = tid + (r << 8);
      int p = j & (Ls - 1);
      int q = j >> s;
      float rev = crev * (float)p;
      float sw = __builtin_amdgcn_sinf(rev);
      float cw = __builtin_amdgcn_cosf(rev);
      float2 a = src[j];
      float2 b = src[j + 1024];
      float tr = b.x*cw - b.y*sw;
      float ti = b.x*sw + b.y*cw;
      int o0 = (q << (s+1)) + p;
      dst[o0]      = f2(a.x + tr, a.y + ti);
      dst[o0 + Ls] = f2(a.x - tr, a.y - ti);
    }
    float2* t = src; src = dst; dst = t;
  }
  __syncthreads();
  return src;
}

// Packed spectrum Z (M=2048) -> rfft bins X[0..2048] of length-4096 real seq,
// stored fp16 to global row; zero the pad bins 2049..2055.
__device__ void unpack_store(const float2* Z, __half2* out, int tid){
  for (int k = tid; k < 2048; k += THREADS){
    float2 zk = Z[k];
    float2 zm = Z[(2048 - k) & 2047];
    float ar =  0.5f*(zk.x + zm.x);
    float ai =  0.5f*(zk.y - zm.y);
    float br =  0.5f*(zk.y + zm.y);
    float bi = -0.5f*(zk.x - zm.x);
    float rev = -(float)k * (1.0f/4096.0f);   // W_4096^k
    float sw = __builtin_amdgcn_sinf(rev);
    float cw = __builtin_amdgcn_cosf(rev);
    out[k] = pack2(ar + cw*br - sw*bi, ai + cw*bi + sw*br);
  }
  if (tid == 0){
    float2 z0 = Z[0];
    out[2048] = pack2(z0.x - z0.y, 0.0f);     // Nyquist
  }
  if (tid >= 1 && tid < 8) out[2048 + tid] = pack2(0.0f, 0.0f);
}

// Weight FFT for o-chunk: local row = o_local*128+i, global o = o_base+o_local.
__global__ __launch_bounds__(THREADS) void kfft_w(const float* __restrict__ w,
                                                  __half2* __restrict__ Wc, int o_base){
  __shared__ float2 A[2048]; __shared__ float2 B[2048];
  int lr = blockIdx.x;
  int grow = (o_base + (lr >> 7)) * 128 + (lr & 127);
  const float2* wv = (const float2*)(w + (size_t)grow * 2048);
  for (int n = threadIdx.x; n < 2048; n += THREADS)
    A[n] = (n < 1024) ? wv[n] : f2(0.f, 0.f);
  float2* Z = fft2048(A, B, threadIdx.x, -1.0f);
  unpack_store(Z, Wc + (size_t)lr * FP, threadIdx.x);
}

// Signal block FFT for bb-chunk: local row = bb_local*128+i, bb = bb_base+bb_local,
// bb = b*4+blk. x[m]=s_pad[blk*2048+m]; float2 idx q = n + blk*1024 - 512.
__global__ __launch_bounds__(THREADS) void kfft_s(const float* __restrict__ sig,
                                                  __half2* __restrict__ Xc, int bb_base){
  __shared__ float2 A[2048]; __shared__ float2 B[2048];
  int lr = blockIdx.x;
  int bb = bb_base + (lr >> 7), i = lr & 127;
  int b = bb >> 2, blk = bb & 3;
  const float2* sv = (const float2*)(sig + (size_t)(b*128 + i) * 8192);
  for (int n = threadIdx.x; n < 2048; n += THREADS){
    int q = n + blk*1024 - 512;
    A[n] = (q >= 0 && q < 4096) ? sv[q] : f2(0.f, 0.f);
  }
  float2* Z = fft2048(A, B, threadIdx.x, -1.0f);
  unpack_store(Z, Xc + (size_t)lr * FP, threadIdx.x);
}

// Y[bb,o,f] = sum_i X[bb,i,f]*conj(W[o,i,f]).  Tile: 8f x 16bb x TO o.
// grid = (BC/16, FP/8, OC/TO). Yc row = bb_local*OC + o_local.
template<int TO>
__global__ __launch_bounds__(THREADS) void keinsum(const __half2* __restrict__ Xc,
                                                   const __half2* __restrict__ Wc,
                                                   __half2* __restrict__ Yc, int OC){
  constexpr int OGN = TO/4;       // og groups
  constexpr int BB_PER = TO/8;    // bb per thread (bg groups = 128/TO)
  __shared__ float2 Xs[16*64];    // [bb][ii*8+f]
  __shared__ float2 Ws[TO*67];    // [o][ii*8+f], stride 67
  const int bb0 = blockIdx.x * 16;
  const int f0  = blockIdx.y * 8;
  const int o0  = blockIdx.z * TO;
  const int tid = threadIdx.x;
  const int f_id = tid & 7;
  const int g  = tid >> 3;
  const int og = g & (OGN - 1);
  const int bg = g / OGN;
  float2 acc[BB_PER][4];
  #pragma unroll
  for (int a_ = 0; a_ < BB_PER; ++a_)
    #pragma unroll
    for (int b_ = 0; b_ < 4; ++b_) acc[a_][b_] = f2(0.f, 0.f);

  for (int ic = 0; ic < 16; ++ic){
    __syncthreads();
    #pragma unroll
    for (int l = 0; l < TO/16; ++l){      // W chunk: TO*16 float4-sized pieces
      int u = l*THREADS + tid;
      int o = u >> 4, ii = (u >> 1) & 7, c = u & 1;
      H2x4 v = *(const H2x4*)(Wc + (size_t)((o0 + o)*128 + ic*8 + ii)*FP + f0 + c*4);
      #pragma unroll
      for (int j = 0; j < 4; ++j) Ws[o*67 + ii*8 + c*4 + j] = unpack2(v.h[j]);
    }
    {                                     // X chunk: 256 pieces, 1 iter
      int u = tid;
      int bbi = u >> 4, ii = (u >> 1) & 7, c = u & 1;
      H2x4 v = *(const H2x4*)(Xc + (size_t)((bb0 + bbi)*128 + ic*8 + ii)*FP + f0 + c*4);
      #pragma unroll
      for (int j = 0; j < 4; ++j) Xs[bbi*64 + ii*8 + c*4 + j] = unpack2(v.h[j]);
    }
    __syncthreads();
    #pragma unroll
    for (int ii = 0; ii < 8; ++ii){
      float2 xv[BB_PER], wv[4];
      #pragma unroll
      for (int bj = 0; bj < BB_PER; ++bj) xv[bj] = Xs[(bg*BB_PER + bj)*64 + ii*8 + f_id];
      #pragma unroll
      for (int oj = 0; oj < 4; ++oj) wv[oj] = Ws[(og*4 + oj)*67 + ii*8 + f_id];
      #pragma unroll
      for (int bj = 0; bj < BB_PER; ++bj)
        #pragma unroll
        for (int oj = 0; oj < 4; ++oj){
          acc[bj][oj].x += xv[bj].x*wv[oj].x + xv[bj].y*wv[oj].y;  // X*conj(W)
          acc[bj][oj].y += xv[bj].y*wv[oj].x - xv[bj].x*wv[oj].y;
        }
    }
  }
  #pragma unroll
  for (int bj = 0; bj < BB_PER; ++bj)
    #pragma unroll
    for (int oj = 0; oj < 4; ++oj){
      int row = (bb0 + bg*BB_PER + bj)*OC + (o0 + og*4 + oj);
      Yc[(size_t)row*FP + f0 + f_id] = pack2(acc[bj][oj].x, acc[bj][oj].y);
    }
}

// Inverse real FFT + scatter + bias. lr = bb_local*OC + o_local.
__global__ __launch_bounds__(THREADS) void kifft(const __half2* __restrict__ Yc,
                                                 const float* __restrict__ bias,
                                                 float* __restrict__ out,
                                                 int bb_base, int o_base, int oc_shift){
  __shared__ float2 A[2048]; __shared__ float2 B[2048];
  __shared__ float XMs;
  int lr = blockIdx.x;
  int OCm = (1 << oc_shift) - 1;
  int bb = bb_base + (lr >> oc_shift);
  int o  = o_base + (lr & OCm);
  int b = bb >> 2, blk = bb & 3;
  int tid = threadIdx.x;
  const __half2* Y = Yc + (size_t)lr * FP;
  #pragma unroll
  for (int l = 0; l < 2; ++l){
    int u = l*THREADS + tid;            // 4-bin piece
    H2x4 v = *(const H2x4*)(Y + u*4);
    #pragma unroll
    for (int j = 0; j < 4; ++j) B[u*4 + j] = unpack2(v.h[j]);
  }
  if (tid == 0) XMs = __low2float(Y[2048]);
  __syncthreads();
  for (int k = tid; k < 2048; k += THREADS){   // rebuild packed spectrum Z
    float2 xk = B[k];
    float2 xm = (k == 0) ? f2(XMs, 0.f) : B[2048 - k];
    float ar = 0.5f*(xk.x + xm.x);
    float ai = 0.5f*(xk.y - xm.y);
    float dr = 0.5f*(xk.x - xm.x);
    float di = 0.5f*(xk.y + xm.y);
    float rev = (float)k * (1.0f/4096.0f);     // W_4096^{-k}
    float sw = __builtin_amdgcn_sinf(rev);
    float cw = __builtin_amdgcn_cosf(rev);
    float br = dr*cw - di*sw;
    float bi = dr*sw + di*cw;
    A[k] = f2(ar - bi, ai + br);               // Z = A + jB
  }
  float2* z = fft2048(A, B, tid, +1.0f);
  const float s = 1.0f/2048.0f;
  const float bv = bias[o];
  float* op = out + (size_t)(b*128 + o)*8193 + blk*2048;
  for (int n = tid; n < 2048; n += THREADS){
    if (n < 1024){
      op[2*n]     = z[n].x*s + bv;
      op[2*n + 1] = z[n].y*s + bv;
    } else if (n == 1024 && blk == 3){
      op[2048] = z[n].x*s + bv;                // final sample t = 8192
    }
  }
}

extern "C" void kernel_launch(void* const* d_in, const int* in_sizes, int n_in,
                              void* d_out, int out_size, void* d_ws, size_t ws_size,
                              hipStream_t stream){
  (void)in_sizes; (void)n_in; (void)out_size;
  const float* sig  = (const float*)d_in[0];
  const float* wgt  = (const float*)d_in[1];
  const float* bias = (const float*)d_in[2];
  float* out = (float*)d_out;
  const size_t rowb = (size_t)FP * sizeof(__half2);  // 8224 B per spectral row

  // Pick largest (OC, BC) chunking that fits ws_size.
  static const int modes[7][2] = {{128,128},{128,64},{128,32},{128,16},{64,16},{32,16},{16,16}};
  int OC = 0, BC = 0;
  for (int m = 0; m < 7; ++m){
    size_t need = ((size_t)modes[m][0]*128 + (size_t)modes[m][1]*128 +
                   (size_t)modes[m][1]*modes[m][0]) * rowb;
    if (need <= ws_size){ OC = modes[m][0]; BC = modes[m][1]; break; }
  }
  if (!OC) return;  // ws too small even for 35.8 MB plan — fail loudly via poison
  int ocs = 0; while ((1 << ocs) != OC) ++ocs;

  char* ws = (char*)d_ws;
  __half2* Wc = (__half2*)ws;
  __half2* Xc = (__half2*)(ws + (size_t)OC*128*rowb);
  __half2* Yc = (__half2*)(ws + ((size_t)OC*128 + (size_t)BC*128)*rowb);

  for (int ob = 0; ob < 128; ob += OC){
    hipLaunchKernelGGL(kfft_w, dim3(OC*128), dim3(THREADS), 0, stream, wgt, Wc, ob);
    for (int bbb = 0; bbb < 128; bbb += BC){
      hipLaunchKernelGGL(kfft_s, dim3(BC*128), dim3(THREADS), 0, stream, sig, Xc, bbb);
      dim3 ge(BC/16, FP/8, OC >= 64 ? OC/64 : 1);
      if (OC >= 64)
        hipLaunchKernelGGL(HIP_KERNEL_NAME(keinsum<64>), ge, dim3(THREADS), 0, stream, Xc, Wc, Yc, OC);
      else if (OC == 32)
        hipLaunchKernelGGL(HIP_KERNEL_NAME(keinsum<32>), ge, dim3(THREADS), 0, stream, Xc, Wc, Yc, OC);
      else
        hipLaunchKernelGGL(HIP_KERNEL_NAME(keinsum<16>), ge, dim3(THREADS), 0, stream, Xc, Wc, Yc, OC);
      hipLaunchKernelGGL(kifft, dim3(BC*OC), dim3(THREADS), 0, stream, Yc, bias, out, bbb, ob, ocs);
    }
  }
}